// Round 11
// baseline (175.184 us; speedup 1.0000x reference)
//
#include <hip/hip_runtime.h>

#define C 256
#define N 4096
#define CPG 8
#define GE (CPG * N)
#define JL 2048               // keys per split (split-K = 2)

constexpr float EPS = 1e-5f;
// 32^-0.25 * sqrt(log2(e)) : folded so P = exp2(q'.k') = exp(q.k/sqrt(32))
constexpr float QK_SCALE_E = 0.50500979f;

typedef float f32x4 __attribute__((ext_vector_type(4)));
typedef short s16x8 __attribute__((ext_vector_type(8)));

__device__ __forceinline__ short f2bf(float f) {
    union { float f; unsigned u; } v; v.f = f;
    unsigned r = v.u + 0x7FFFu + ((v.u >> 16) & 1u);  // RNE
    return (short)(r >> 16);
}
__device__ __forceinline__ float bf2f(short s) {
    union { unsigned u; float f; } v; v.u = ((unsigned)(unsigned short)s) << 16;
    return v.f;
}

// ---------------- K1: fused GroupNorm partial stats + weight convert ----------------
__global__ __launch_bounds__(256) void k_prep(const float* __restrict__ x,
        const float* __restrict__ wq, const float* __restrict__ wk,
        const float* __restrict__ wv, const float* __restrict__ wo,
        float2* __restrict__ partials, short* __restrict__ wqkvb,
        short* __restrict__ wob) {
    if (blockIdx.x < 256) {
        int q = blockIdx.x & 3, g = (blockIdx.x >> 2) & 31, b = (int)blockIdx.x >> 7;
        size_t base = (size_t)(b * C + g * CPG) * N + q * (GE / 4);
        const float* xp = x + base;
        int tid = threadIdx.x;
        float sum = 0.f, ss = 0.f;
        for (int i = tid * 4; i < GE / 4; i += 1024) {
            float4 v = *(const float4*)(xp + i);
            sum += (v.x + v.y) + (v.z + v.w);
            ss  += (v.x * v.x + v.y * v.y) + (v.z * v.z + v.w * v.w);
        }
        #pragma unroll
        for (int o = 32; o; o >>= 1) {
            sum += __shfl_down(sum, o, 64);
            ss  += __shfl_down(ss, o, 64);
        }
        __shared__ float red[8];
        int wid = tid >> 6;
        if ((tid & 63) == 0) { red[wid] = sum; red[4 + wid] = ss; }
        __syncthreads();
        if (tid == 0) {
            sum = red[0] + red[1] + red[2] + red[3];
            ss  = red[4] + red[5] + red[6] + red[7];
            partials[(b * 32 + g) * 4 + q] = make_float2(sum, ss);
        }
    } else {
        int i = (blockIdx.x - 256) * 256 + threadIdx.x;   // 0..262143
        if (i < 65536)       wqkvb[i] = f2bf(wq[i]);
        else if (i < 131072) wqkvb[i] = f2bf(wk[i - 65536]);
        else if (i < 196608) wqkvb[i] = f2bf(wv[i - 131072]);
        else                 wob[i - 196608] = f2bf(wo[i - 196608]);
    }
}

// ---------------- K4: QKV projection with fused GroupNorm staging ----------------
// k_t deleted: thread t normalizes channels (2t, 2t+1) x 32 n-positions straight
// from fp32 x into the swizzled LDS B-tile (bitwise-identical values to the old
// xnT path). Epilogue scratch aliases the dead B-tile after the MFMA loop.
__global__ __launch_bounds__(256) void k_qkv(const short* __restrict__ wqkvb,
        const float* __restrict__ x, const float* __restrict__ gs,
        const float* __restrict__ gb, const float2* __restrict__ partials,
        const float* __restrict__ bq, const float* __restrict__ bk,
        const float* __restrict__ bv,
        short* __restrict__ qT, short* __restrict__ kT, short* __restrict__ vB) {
    __shared__ __align__(16) short bs[64 * 256];      // 32KB swizzled B-tile
    int mb = blockIdx.x, nb = blockIdx.y, b = blockIdx.z;
    int m0 = mb * 64, n0 = nb * 64;
    int t = threadIdx.x;
    int wid = t >> 6, lane = t & 63;
    int lr = lane & 15, lg = lane >> 4;
    int mw = m0 + wid * 16;

    const short* ap_ = wqkvb + (mw + lr) * C + lg * 8;
    s16x8 af[8];
    #pragma unroll
    for (int kk = 0; kk < 8; ++kk)
        af[kk] = *(const s16x8*)(ap_ + kk * 32);

    // ---- stage: GroupNorm-normalize x into swizzled [n][c] B-tile ----
    {
        int tl = t & 127;          // 0..127
        int c0 = tl * 2;           // even channel, pair (c0, c0+1)
        int nh = t >> 7;           // n-half: 0 or 1
        int bg = b * 32 + (c0 >> 3);
        float2 p0 = partials[bg * 4 + 0], p1 = partials[bg * 4 + 1];
        float2 p2 = partials[bg * 4 + 2], p3 = partials[bg * 4 + 3];
        float sum = (p0.x + p1.x) + (p2.x + p3.x);
        float ss  = (p0.y + p1.y) + (p2.y + p3.y);
        float mean = sum * (1.f / GE);
        float var  = ss * (1.f / GE) - mean * mean;
        float rstd = rsqrtf(var + EPS);
        float sc0 = gs[c0] * rstd,     bi0 = gb[c0] - mean * sc0;
        float sc1 = gs[c0 + 1] * rstd, bi1 = gb[c0 + 1] - mean * sc1;
        const float* xp0 = x + (size_t)(b * C + c0) * N + n0 + nh * 32;
        const float* xp1 = xp0 + N;
        #pragma unroll
        for (int i = 0; i < 8; ++i) {
            float4 v0 = ((const float4*)xp0)[i];
            float4 v1 = ((const float4*)xp1)[i];
            #pragma unroll
            for (int j = 0; j < 4; ++j) {
                int n = nh * 32 + i * 4 + j;
                float f0 = ((const float*)&v0)[j] * sc0 + bi0;
                float f1 = ((const float*)&v1)[j] * sc1 + bi1;
                unsigned lo = (unsigned)(unsigned short)f2bf(f0);
                unsigned hi = (unsigned)(unsigned short)f2bf(f1);
                unsigned pk = lo | (hi << 16);
                int soff = (((c0 >> 3) ^ (n & 7)) * 8) + (c0 & 7);
                *(unsigned*)&bs[n * 256 + soff] = pk;
            }
        }
    }
    __syncthreads();

    f32x4 acc[4] = {{0,0,0,0},{0,0,0,0},{0,0,0,0},{0,0,0,0}};
    #pragma unroll
    for (int kk = 0; kk < 8; ++kk) {
        int sb = kk * 4;
        #pragma unroll
        for (int f = 0; f < 4; ++f) {
            int row = f * 16 + lr;
            s16x8 xf = *(const s16x8*)&bs[row * 256 + (((sb + lg) ^ (lr & 7)) * 8)];
            acc[f] = __builtin_amdgcn_mfma_f32_16x16x32_bf16(af[kk], xf, acc[f], 0, 0, 0);
        }
    }
    __syncthreads();   // bs dead as B-tile; epilogue reuses it

    int kind = mb >> 2;                  // 0=q 1=k 2=v
    const float* bias = kind == 0 ? bq : (kind == 1 ? bk : bv);
    int mloc = mw - kind * 256;
    float bvals[4];
    #pragma unroll
    for (int r = 0; r < 4; ++r) bvals[r] = bias[mloc + 4 * lg + r];
    int h = mloc >> 5;
    if (kind == 2) {
        // transpose 64ch x 64n through swizzled LDS, then coalesced 16B stores
        short (*vt)[64] = (short(*)[64])bs;
        #pragma unroll
        for (int f = 0; f < 4; ++f)
            #pragma unroll
            for (int r = 0; r < 4; ++r) {
                int rl = wid * 16 + 4 * lg + r;     // channel-local 0..63
                int cn = f * 16 + lr;               // n-local 0..63
                int sl = cn >> 3, off = cn & 7;
                vt[rl][((sl ^ (rl & 7)) * 8) + off] = f2bf(acc[f][r] + bvals[r]);
            }
        __syncthreads();
        int mlocB = mb * 64 - 512;                  // block channel base
        int h0 = mlocB >> 5;
        int rr = t >> 2, sl = t & 3;
        int h2 = h0 + (rr >> 5), dd = rr & 31;
        short* vdst = vB + ((size_t)((b * 8 + h2) * 32 + dd)) * N + n0;
        s16x8 w0v = *(const s16x8*)&vt[rr][(sl ^ (rr & 7)) * 8];
        s16x8 w1v = *(const s16x8*)&vt[rr][((sl + 4) ^ (rr & 7)) * 8];
        *(s16x8*)(vdst + sl * 8) = w0v;
        *(s16x8*)(vdst + (sl + 4) * 8) = w1v;
    } else {
        short (*ltw)[16] = (short(*)[16])&bs[wid * 1024];   // per-wave 64x16
        short* dst = (kind == 0) ? qT : kT;
        #pragma unroll
        for (int f = 0; f < 4; ++f)
            #pragma unroll
            for (int r = 0; r < 4; ++r)
                ltw[f * 16 + lr][4 * lg + r] =
                    f2bf((acc[f][r] + bvals[r]) * QK_SCALE_E);
        int ln = lane;
        s16x8 w0 = *(const s16x8*)&ltw[ln][0];
        s16x8 w1 = *(const s16x8*)&ltw[ln][8];
        short* op = dst + ((size_t)(b * 8 + h) * N + n0 + ln) * 32 + (mloc & 16);
        *(s16x8*)op = w0;
        *(s16x8*)(op + 8) = w1;
    }
}

// ---------------- K5: LDS-staged double-buffered flash attention + setprio --------
#define EXPB(d, s_) asm("v_exp_f32 %0, %1\n\ts_nop 0" : "=v"(d) : "v"(s_))

#define TILE_BODY() do {                                                          \
    f32x4 s0 = __builtin_amdgcn_mfma_f32_16x16x32_bf16(bk0, aq, zero, 0, 0, 0);   \
    f32x4 s1 = __builtin_amdgcn_mfma_f32_16x16x32_bf16(bk1, aq, zero, 0, 0, 0);   \
    float e00, e01, e02, e03, e10, e11, e12, e13;                                 \
    EXPB(e00, s0[0]); EXPB(e01, s0[1]); EXPB(e02, s0[2]); EXPB(e03, s0[3]);       \
    EXPB(e10, s1[0]); EXPB(e11, s1[1]); EXPB(e12, s1[2]); EXPB(e13, s1[3]);       \
    unsigned w0, w1, w2, w3;                                                      \
    asm("v_cvt_pk_bf16_f32 %0, %1, %2" : "=v"(w0) : "v"(e00), "v"(e01));          \
    asm("v_cvt_pk_bf16_f32 %0, %1, %2" : "=v"(w1) : "v"(e02), "v"(e03));          \
    asm("v_cvt_pk_bf16_f32 %0, %1, %2" : "=v"(w2) : "v"(e10), "v"(e11));          \
    asm("v_cvt_pk_bf16_f32 %0, %1, %2" : "=v"(w3) : "v"(e12), "v"(e13));          \
    asm("v_permlane32_swap_b32 %0, %1" : "+v"(w0), "+v"(w2));                     \
    asm("v_permlane16_swap_b32 %0, %1" : "+v"(w0), "+v"(w2));                     \
    asm("v_permlane32_swap_b32 %0, %1" : "+v"(w1), "+v"(w3));                     \
    asm("v_permlane16_swap_b32 %0, %1" : "+v"(w1), "+v"(w3));                     \
    union { int4 i4; s16x8 s8; } apu;                                             \
    apu.i4 = make_int4((int)w0, (int)w1, (int)w2, (int)w3);                       \
    s16x8 ap = apu.s8;                                                            \
    lac = __builtin_amdgcn_mfma_f32_16x16x32_bf16(ap, ones, lac, 0, 0, 0);        \
    o0  = __builtin_amdgcn_mfma_f32_16x16x32_bf16(ap, bv0, o0, 0, 0, 0);          \
    o1  = __builtin_amdgcn_mfma_f32_16x16x32_bf16(ap, bv1, o1, 0, 0, 0);          \
} while (0)

__global__ __launch_bounds__(256, 8) void k_attn(const short* __restrict__ qT,
        const short* __restrict__ kT, const short* __restrict__ vB,
        short* __restrict__ po0, short* __restrict__ po1,
        float* __restrict__ pl) {
    __shared__ __align__(16) short pool[8192];
    int xb  = blockIdx.x;
    int rm  = (xb & 7) * 128 + (xb >> 3);      // XCD-bijective swizzle
    int bh  = rm >> 6;
    int wid = threadIdx.x >> 6;
    int i0  = (rm & 63) * 64 + wid * 16;
    int s   = blockIdx.y;
    int jb  = s * JL;
    int lane = threadIdx.x & 63;
    int lr = lane & 15, lg = lane >> 4;
    const short* qTb = qT + (size_t)bh * N * 32;
    const short* kTb = kT + (size_t)bh * N * 32;
    const short* vBb = vB + (size_t)bh * 32 * N;

    s16x8 aq = *(const s16x8*)(qTb + (i0 + lr) * 32 + lg * 8);
    s16x8 ones;
    #pragma unroll
    for (int e = 0; e < 8; ++e) ones[e] = (short)0x3F80;

    f32x4 o0 = {0,0,0,0}, o1 = {0,0,0,0}, lac = {0,0,0,0};
    const f32x4 zero = {0,0,0,0};

    int krow  = 16 * wid + (lane >> 2);
    int kslot = lane & 3;
    const short* kg = kTb + (size_t)(jb + krow) * 32 + kslot * 8;
    int kw_ofs = krow * 32 + ((kslot ^ (krow & 3)) * 8);

    int vrow  = 8 * wid + (lane >> 3);
    int vslot = lane & 7;
    const short* vg = vBb + (size_t)vrow * N + jb + vslot * 8;
    int vw_ofs = vrow * 64 + ((vslot ^ (vrow & 7)) * 8);

    int kr_base = lr * 32 + ((lg ^ (lr & 3)) * 8);
    int vr0 = lr * 64, vr1 = (16 + lr) * 64;
    int sw0 = ((0 + lg) ^ (lr & 7)) * 8;
    int sw1 = ((4 + lg) ^ (lr & 7)) * 8;

    {
        s16x8 kreg = *(const s16x8*)kg;
        s16x8 vreg = *(const s16x8*)vg;
        *(s16x8*)&pool[kw_ofs] = kreg;
        *(s16x8*)&pool[4096 + vw_ofs] = vreg;
    }
    __syncthreads();

    for (int t = 0; t < 32; ++t) {
        int p = t & 1;
        s16x8 nk, nv;
        if (t < 31) {
            nk = *(const s16x8*)(kg + (t + 1) * 2048);
            nv = *(const s16x8*)(vg + (t + 1) * 64);
        }
        const short* lkp = &pool[p * 2048];
        const short* lvp = &pool[4096 + p * 2048];
        __builtin_amdgcn_s_setprio(1);
        {
            s16x8 bk0 = *(const s16x8*)(lkp + kr_base);
            s16x8 bk1 = *(const s16x8*)(lkp + 512 + kr_base);
            s16x8 bv0 = *(const s16x8*)(lvp + vr0 + sw0);
            s16x8 bv1 = *(const s16x8*)(lvp + vr1 + sw0);
            TILE_BODY();
        }
        {
            s16x8 bk0 = *(const s16x8*)(lkp + 1024 + kr_base);
            s16x8 bk1 = *(const s16x8*)(lkp + 1536 + kr_base);
            s16x8 bv0 = *(const s16x8*)(lvp + vr0 + sw1);
            s16x8 bv1 = *(const s16x8*)(lvp + vr1 + sw1);
            TILE_BODY();
        }
        __builtin_amdgcn_s_setprio(0);
        if (t < 31) {
            int q = (t + 1) & 1;
            *(s16x8*)&pool[q * 2048 + kw_ofs] = nk;
            *(s16x8*)&pool[4096 + q * 2048 + vw_ofs] = nv;
        }
        __syncthreads();
    }

    #pragma unroll
    for (int r = 0; r < 4; ++r) {
        pool[wid * 640 + (4 * lg + r) * 40 + lr]      = f2bf(o0[r]);
        pool[wid * 640 + (4 * lg + r) * 40 + 16 + lr] = f2bf(o1[r]);
    }
    if (lr == 0) {
        float* plp = pl + ((size_t)(s * 16 + bh)) * N + i0;
        #pragma unroll
        for (int r = 0; r < 4; ++r) plp[4 * lg + r] = lac[r];
    }
    short* pob = s ? po1 : po0;
    int il = lane >> 2, seg = lane & 3;
    s16x8 w = *(const s16x8*)&pool[wid * 640 + il * 40 + seg * 8];
    short* op = pob + ((size_t)bh * N + i0 + il) * 32 + seg * 8;
    *(s16x8*)op = w;
}

// ---------------- K6: out projection + residual; merge folded into staging --------
__global__ __launch_bounds__(256) void k_out(const short* __restrict__ wob,
        const short* __restrict__ po0, const short* __restrict__ po1,
        const float* __restrict__ pl, const float* __restrict__ bo,
        const float* __restrict__ x, float* __restrict__ out) {
    __shared__ __align__(16) short bs[8 * 32 * 32];   // 16KB: 8 h-tiles swizzled
    int mb = blockIdx.x, nb = blockIdx.y, b = blockIdx.z;
    int n0 = nb * 32;
    int t = threadIdx.x;
    int wid = t >> 6, lane = t & 63;
    int lr = lane & 15, lg = lane >> 4;
    int mw = mb * 64 + wid * 16;

    const short* ap_ = wob + (mw + lr) * C + lg * 8;
    s16x8 af[8];
    #pragma unroll
    for (int h = 0; h < 8; ++h) af[h] = *(const s16x8*)(ap_ + h * 32);

    {
        int h = t >> 5, idx = t & 31;
        size_t rb = ((size_t)(b * 8 + h)) * N + n0;
        const short* g0 = po0 + rb * 32;
        const short* g1 = po1 + rb * 32;
        const float* pl0 = pl + rb;
        const float* pl1 = pl + ((size_t)(16 + b * 8 + h)) * N + n0;
        #pragma unroll
        for (int i = 0; i < 4; ++i) {
            int chunk = idx + 32 * i;           // 0..127
            int r = chunk >> 2, sl = chunk & 3; // r: n-local 0..31
            s16x8 v0 = *(const s16x8*)(g0 + r * 32 + sl * 8);
            s16x8 v1 = *(const s16x8*)(g1 + r * 32 + sl * 8);
            float inv = 1.f / (pl0[r] + pl1[r]);
            s16x8 w;
            #pragma unroll
            for (int e = 0; e < 8; ++e)
                w[e] = f2bf((bf2f(v0[e]) + bf2f(v1[e])) * inv);
            *(s16x8*)&bs[h * 1024 + r * 32 + ((sl ^ (r & 3)) * 8)] = w;
        }
    }
    __syncthreads();

    f32x4 acc[2] = {{0,0,0,0},{0,0,0,0}};
    #pragma unroll
    for (int h = 0; h < 8; ++h) {
        #pragma unroll
        for (int f = 0; f < 2; ++f) {
            int row = f * 16 + lr;
            s16x8 xf = *(const s16x8*)&bs[h * 1024 + row * 32 + ((lg ^ (lr & 3)) * 8)];
            acc[f] = __builtin_amdgcn_mfma_f32_16x16x32_bf16(af[h], xf, acc[f], 0, 0, 0);
        }
    }

    float bvals[4];
    #pragma unroll
    for (int r = 0; r < 4; ++r) bvals[r] = bo[mw + 4 * lg + r];
    #pragma unroll
    for (int f = 0; f < 2; ++f) {
        int n = n0 + f * 16 + lr;
        #pragma unroll
        for (int r = 0; r < 4; ++r) {
            size_t idx = (size_t)(b * C + mw + 4 * lg + r) * N + n;
            out[idx] = acc[f][r] + bvals[r] + x[idx];
        }
    }
}

extern "C" void kernel_launch(void* const* d_in, const int* in_sizes, int n_in,
                              void* d_out, int out_size, void* d_ws, size_t ws_size,
                              hipStream_t stream) {
    const float* x  = (const float*)d_in[0];
    const float* gs = (const float*)d_in[1];
    const float* gb = (const float*)d_in[2];
    const float* wq = (const float*)d_in[3];
    const float* bq = (const float*)d_in[4];
    const float* wk = (const float*)d_in[5];
    const float* bk = (const float*)d_in[6];
    const float* wv = (const float*)d_in[7];
    const float* bv = (const float*)d_in[8];
    const float* wo = (const float*)d_in[9];
    const float* bo = (const float*)d_in[10];
    float* out = (float*)d_out;
    char* ws = (char*)d_ws;

    // Total ws usage: 0x14B0000 = 21.69 MB (< 22.02 MB proven safe).
    float2* partials = (float2*)(ws);           // 2 KB
    short*  wqkvb = (short*)(ws + 0x1000);      // 384 KB, dead after k_qkv
    float*  pl    = (float*)(ws + 0x1000);      // 512 KB, overlays dead wqkvb
    short*  wob   = (short*)(ws + 0x81000);     // 128 KB
    short*  po1   = (short*)(ws + 0xB0000);     // 4 MB (xnT slot, now unused by qkv)
    short*  qT    = (short*)(ws + 0x4B0000);    // 4 MB [bh][n][32]
    short*  kT    = (short*)(ws + 0x8B0000);    // 4 MB [bh][n][32]
    short*  vB    = (short*)(ws + 0xCB0000);    // 4 MB [bh][32][n]
    short*  po0   = (short*)(ws + 0x10B0000);   // 4 MB [bh][n][32]

    k_prep <<<1280, 256, 0, stream>>>(x, wq, wk, wv, wo, partials, wqkvb, wob);
    k_qkv  <<<dim3(12, 64, 2), 256, 0, stream>>>(wqkvb, x, gs, gb, partials,
                                                 bq, bk, bv, qT, kT, vB);
    k_attn <<<dim3(1024, 2), 256, 0, stream>>>(qT, kT, vB, po0, po1, pl);
    k_out  <<<dim3(4, 128, 2), 256, 0, stream>>>(wob, po0, po1, pl, bo, x, out);
}

// Round 12
// 156.393 us; speedup vs baseline: 1.1202x; 1.1202x over previous
//
#include <hip/hip_runtime.h>

#define C 256
#define N 4096
#define CPG 8
#define GE (CPG * N)
#define JL 2048               // keys per split (split-K = 2)

constexpr float EPS = 1e-5f;
// 32^-0.25 * sqrt(log2(e)) : folded so P = exp2(q'.k') = exp(q.k/sqrt(32))
constexpr float QK_SCALE_E = 0.50500979f;

typedef float f32x4 __attribute__((ext_vector_type(4)));
typedef short s16x8 __attribute__((ext_vector_type(8)));

__device__ __forceinline__ short f2bf(float f) {
    union { float f; unsigned u; } v; v.f = f;
    unsigned r = v.u + 0x7FFFu + ((v.u >> 16) & 1u);  // RNE
    return (short)(r >> 16);
}
__device__ __forceinline__ float bf2f(short s) {
    union { unsigned u; float f; } v; v.u = ((unsigned)(unsigned short)s) << 16;
    return v.f;
}

// ---------------- K1: GroupNorm partial stats (4 n-chunks per (b,g)) ----------------
__global__ __launch_bounds__(256) void k_stats(const float* __restrict__ x,
                                               float2* __restrict__ partials) {
    int q = blockIdx.x & 3, g = (blockIdx.x >> 2) & 31, b = blockIdx.x >> 7;
    size_t base = (size_t)(b * C + g * CPG) * N + q * (GE / 4);
    const float* xp = x + base;
    int tid = threadIdx.x;
    float sum = 0.f, ss = 0.f;
    for (int i = tid * 4; i < GE / 4; i += 1024) {
        float4 v = *(const float4*)(xp + i);
        sum += (v.x + v.y) + (v.z + v.w);
        ss  += (v.x * v.x + v.y * v.y) + (v.z * v.z + v.w * v.w);
    }
    #pragma unroll
    for (int o = 32; o; o >>= 1) {
        sum += __shfl_down(sum, o, 64);
        ss  += __shfl_down(ss, o, 64);
    }
    __shared__ float red[8];
    int wid = tid >> 6;
    if ((tid & 63) == 0) { red[wid] = sum; red[4 + wid] = ss; }
    __syncthreads();
    if (tid == 0) {
        sum = red[0] + red[1] + red[2] + red[3];
        ss  = red[4] + red[5] + red[6] + red[7];
        partials[(b * 32 + g) * 4 + q] = make_float2(sum, ss);
    }
}

// ---------------- K2: weights fp32 -> bf16 ----------------
__global__ __launch_bounds__(256) void k_wcvt(const float* __restrict__ wq,
        const float* __restrict__ wk, const float* __restrict__ wv,
        const float* __restrict__ wo, short* __restrict__ wqkvb,
        short* __restrict__ wob) {
    int i = blockIdx.x * 256 + threadIdx.x;   // grid 1024 -> 262144
    if (i < 65536)       wqkvb[i] = f2bf(wq[i]);
    else if (i < 131072) wqkvb[i] = f2bf(wk[i - 65536]);
    else if (i < 196608) wqkvb[i] = f2bf(wv[i - 131072]);
    else                 wob[i - 196608] = f2bf(wo[i - 196608]);
}

// ---------------- K3: normalize + transpose -> xnT[b][n][c] bf16 ----------------
__global__ __launch_bounds__(256) void k_t(const float* __restrict__ x,
        const float* __restrict__ gs, const float* __restrict__ gb,
        const float2* __restrict__ partials, short* __restrict__ xnT) {
    __shared__ __align__(16) short lt[64][72];   // [n_local][c_local], pad 8
    int id = blockIdx.x;
    int b  = id >> 8;            // 2
    int ct = (id >> 6) & 3;      // 4 c-tiles of 64
    int nt = id & 63;            // 64 n-tiles of 64
    int c0 = ct * 64, n0 = nt * 64;
    int t = threadIdx.x;
    int cc = t >> 2;
    int c = c0 + cc;
    int bg = b * 32 + (c >> 3);
    float2 p0 = partials[bg * 4 + 0], p1 = partials[bg * 4 + 1];
    float2 p2 = partials[bg * 4 + 2], p3 = partials[bg * 4 + 3];
    float sum = (p0.x + p1.x) + (p2.x + p3.x);
    float ss  = (p0.y + p1.y) + (p2.y + p3.y);
    float mean = sum * (1.f / GE);
    float var  = ss * (1.f / GE) - mean * mean;
    float rstd = rsqrtf(var + EPS);
    float sc = gs[c] * rstd;
    float bi = gb[c] - mean * sc;
    const float* xp = x + (size_t)(b * C + c) * N + n0;
    #pragma unroll
    for (int it = 0; it < 4; ++it) {
        int f4 = (t & 3) + it * 4;
        float4 v = *(const float4*)(xp + f4 * 4);
        int nl = f4 * 4;
        lt[nl + 0][cc] = f2bf(v.x * sc + bi);
        lt[nl + 1][cc] = f2bf(v.y * sc + bi);
        lt[nl + 2][cc] = f2bf(v.z * sc + bi);
        lt[nl + 3][cc] = f2bf(v.w * sc + bi);
    }
    __syncthreads();
    int nl = t >> 2, seg = t & 3;
    short* op = xnT + (size_t)(b * N + n0 + nl) * C + c0 + seg * 16;
    s16x8 w0 = *(const s16x8*)&lt[nl][seg * 16];
    s16x8 w1 = *(const s16x8*)&lt[nl][seg * 16 + 8];
    *(s16x8*)op = w0;
    *(s16x8*)(op + 8) = w1;
}

// ---------------- K4: QKV projection, bf16 MFMA GEMM, LDS-staged B ----------------
__global__ __launch_bounds__(256) void k_qkv(const short* __restrict__ wqkvb,
        const short* __restrict__ xnT, const float* __restrict__ bq,
        const float* __restrict__ bk, const float* __restrict__ bv,
        short* __restrict__ qT, short* __restrict__ kT, short* __restrict__ vB) {
    __shared__ __align__(16) short bs[64 * 256];      // 32KB swizzled B-tile
    __shared__ __align__(16) short lt[4][64][16];     // 8KB epilogue scratch
    int mb = blockIdx.x, nb = blockIdx.y, b = blockIdx.z;
    int m0 = mb * 64, n0 = nb * 64;
    int t = threadIdx.x;
    int wid = t >> 6, lane = t & 63;
    int lr = lane & 15, lg = lane >> 4;
    int mw = m0 + wid * 16;

    const short* ap_ = wqkvb + (mw + lr) * C + lg * 8;
    s16x8 af[8];
    #pragma unroll
    for (int kk = 0; kk < 8; ++kk)
        af[kk] = *(const s16x8*)(ap_ + kk * 32);

    {
        int gr = t >> 2;
        const short* gp = xnT + ((size_t)b * N + n0 + gr) * C + (t & 3) * 8;
        #pragma unroll
        for (int i = 0; i < 8; ++i) {
            int sl = (t & 3) + 4 * i;
            s16x8 v = *(const s16x8*)(gp + 32 * i);
            *(s16x8*)&bs[gr * 256 + ((sl ^ (gr & 7)) * 8)] = v;
        }
    }
    __syncthreads();

    f32x4 acc[4] = {{0,0,0,0},{0,0,0,0},{0,0,0,0},{0,0,0,0}};
    #pragma unroll
    for (int kk = 0; kk < 8; ++kk) {
        int sb = kk * 4;
        #pragma unroll
        for (int f = 0; f < 4; ++f) {
            int row = f * 16 + lr;
            s16x8 xf = *(const s16x8*)&bs[row * 256 + (((sb + lg) ^ (lr & 7)) * 8)];
            acc[f] = __builtin_amdgcn_mfma_f32_16x16x32_bf16(af[kk], xf, acc[f], 0, 0, 0);
        }
    }

    int kind = mb >> 2;                  // 0=q 1=k 2=v
    const float* bias = kind == 0 ? bq : (kind == 1 ? bk : bv);
    int mloc = mw - kind * 256;
    float bvals[4];
    #pragma unroll
    for (int r = 0; r < 4; ++r) bvals[r] = bias[mloc + 4 * lg + r];
    int h = mloc >> 5;
    if (kind == 2) {
        // transpose 64ch x 64n through swizzled LDS, then coalesced 16B stores
        short (*vt)[64] = (short(*)[64])lt;
        #pragma unroll
        for (int f = 0; f < 4; ++f)
            #pragma unroll
            for (int r = 0; r < 4; ++r) {
                int rl = wid * 16 + 4 * lg + r;     // channel-local 0..63
                int cn = f * 16 + lr;               // n-local 0..63
                int sl = cn >> 3, off = cn & 7;
                vt[rl][((sl ^ (rl & 7)) * 8) + off] = f2bf(acc[f][r] + bvals[r]);
            }
        __syncthreads();
        int mlocB = mb * 64 - 512;                  // block channel base
        int h0 = mlocB >> 5;
        int rr = t >> 2, sl = t & 3;
        int h2 = h0 + (rr >> 5), dd = rr & 31;
        short* vdst = vB + ((size_t)((b * 8 + h2) * 32 + dd)) * N + n0;
        s16x8 w0v = *(const s16x8*)&vt[rr][(sl ^ (rr & 7)) * 8];
        s16x8 w1v = *(const s16x8*)&vt[rr][((sl + 4) ^ (rr & 7)) * 8];
        *(s16x8*)(vdst + sl * 8) = w0v;
        *(s16x8*)(vdst + (sl + 4) * 8) = w1v;
    } else {
        short* dst = (kind == 0) ? qT : kT;
        #pragma unroll
        for (int f = 0; f < 4; ++f)
            #pragma unroll
            for (int r = 0; r < 4; ++r)
                lt[wid][f * 16 + lr][4 * lg + r] =
                    f2bf((acc[f][r] + bvals[r]) * QK_SCALE_E);
        int ln = lane;
        s16x8 w0 = *(const s16x8*)&lt[wid][ln][0];
        s16x8 w1 = *(const s16x8*)&lt[wid][ln][8];
        short* op = dst + ((size_t)(b * 8 + h) * N + n0 + ln) * 32 + (mloc & 16);
        *(s16x8*)op = w0;
        *(s16x8*)(op + 8) = w1;
    }
}

// ---------------- K5: LDS-staged dbuf flash attention; setprio; unrolled x2 --------
#define EXPB(d, s_) asm("v_exp_f32 %0, %1\n\ts_nop 0" : "=v"(d) : "v"(s_))

#define TILE_BODY() do {                                                          \
    f32x4 s0 = __builtin_amdgcn_mfma_f32_16x16x32_bf16(bk0, aq, zero, 0, 0, 0);   \
    f32x4 s1 = __builtin_amdgcn_mfma_f32_16x16x32_bf16(bk1, aq, zero, 0, 0, 0);   \
    float e00, e01, e02, e03, e10, e11, e12, e13;                                 \
    EXPB(e00, s0[0]); EXPB(e01, s0[1]); EXPB(e02, s0[2]); EXPB(e03, s0[3]);       \
    EXPB(e10, s1[0]); EXPB(e11, s1[1]); EXPB(e12, s1[2]); EXPB(e13, s1[3]);       \
    unsigned w0, w1, w2, w3;                                                      \
    asm("v_cvt_pk_bf16_f32 %0, %1, %2" : "=v"(w0) : "v"(e00), "v"(e01));          \
    asm("v_cvt_pk_bf16_f32 %0, %1, %2" : "=v"(w1) : "v"(e02), "v"(e03));          \
    asm("v_cvt_pk_bf16_f32 %0, %1, %2" : "=v"(w2) : "v"(e10), "v"(e11));          \
    asm("v_cvt_pk_bf16_f32 %0, %1, %2" : "=v"(w3) : "v"(e12), "v"(e13));          \
    asm("v_permlane32_swap_b32 %0, %1" : "+v"(w0), "+v"(w2));                     \
    asm("v_permlane16_swap_b32 %0, %1" : "+v"(w0), "+v"(w2));                     \
    asm("v_permlane32_swap_b32 %0, %1" : "+v"(w1), "+v"(w3));                     \
    asm("v_permlane16_swap_b32 %0, %1" : "+v"(w1), "+v"(w3));                     \
    union { int4 i4; s16x8 s8; } apu;                                             \
    apu.i4 = make_int4((int)w0, (int)w1, (int)w2, (int)w3);                       \
    s16x8 ap = apu.s8;                                                            \
    lac = __builtin_amdgcn_mfma_f32_16x16x32_bf16(ap, ones, lac, 0, 0, 0);        \
    o0  = __builtin_amdgcn_mfma_f32_16x16x32_bf16(ap, bv0, o0, 0, 0, 0);          \
    o1  = __builtin_amdgcn_mfma_f32_16x16x32_bf16(ap, bv1, o1, 0, 0, 0);          \
} while (0)

// One pipeline step: compute from buffer P (compile-time), stage tile TNEXT into
// buffer P^1 (issue-early / write-late), one barrier. DOSTAGE is compile-time.
#define STEP(P, TNEXT, DOSTAGE) do {                                              \
    s16x8 nk, nv;                                                                 \
    if (DOSTAGE) {                                                                \
        nk = *(const s16x8*)(kg + (size_t)(TNEXT) * 2048);                        \
        nv = *(const s16x8*)(vg + (TNEXT) * 64);                                  \
    }                                                                             \
    const short* lkp = &pool[(P) * 2048];                                         \
    const short* lvp = &pool[4096 + (P) * 2048];                                  \
    __builtin_amdgcn_s_setprio(1);                                                \
    {                                                                             \
        s16x8 bk0 = *(const s16x8*)(lkp + kr_base);                               \
        s16x8 bk1 = *(const s16x8*)(lkp + 512 + kr_base);                         \
        s16x8 bv0 = *(const s16x8*)(lvp + vr0 + sw0);                             \
        s16x8 bv1 = *(const s16x8*)(lvp + vr1 + sw0);                             \
        TILE_BODY();                                                              \
    }                                                                             \
    {                                                                             \
        s16x8 bk0 = *(const s16x8*)(lkp + 1024 + kr_base);                        \
        s16x8 bk1 = *(const s16x8*)(lkp + 1536 + kr_base);                        \
        s16x8 bv0 = *(const s16x8*)(lvp + vr0 + sw1);                             \
        s16x8 bv1 = *(const s16x8*)(lvp + vr1 + sw1);                             \
        TILE_BODY();                                                              \
    }                                                                             \
    __builtin_amdgcn_s_setprio(0);                                                \
    if (DOSTAGE) {                                                                \
        *(s16x8*)&pool[((P) ^ 1) * 2048 + kw_ofs] = nk;                           \
        *(s16x8*)&pool[4096 + ((P) ^ 1) * 2048 + vw_ofs] = nv;                    \
    }                                                                             \
    __syncthreads();                                                              \
} while (0)

__global__ __launch_bounds__(256, 8) void k_attn(const short* __restrict__ qT,
        const short* __restrict__ kT, const short* __restrict__ vB,
        short* __restrict__ po0, short* __restrict__ po1,
        float* __restrict__ pl) {
    __shared__ __align__(16) short pool[8192];
    int xb  = blockIdx.x;
    int rm  = (xb & 7) * 128 + (xb >> 3);      // XCD-bijective swizzle
    int bh  = rm >> 6;
    int wid = threadIdx.x >> 6;
    int i0  = (rm & 63) * 64 + wid * 16;
    int s   = blockIdx.y;
    int jb  = s * JL;
    int lane = threadIdx.x & 63;
    int lr = lane & 15, lg = lane >> 4;
    const short* qTb = qT + (size_t)bh * N * 32;
    const short* kTb = kT + (size_t)bh * N * 32;
    const short* vBb = vB + (size_t)bh * 32 * N;

    s16x8 aq = *(const s16x8*)(qTb + (i0 + lr) * 32 + lg * 8);
    s16x8 ones;
    #pragma unroll
    for (int e = 0; e < 8; ++e) ones[e] = (short)0x3F80;

    f32x4 o0 = {0,0,0,0}, o1 = {0,0,0,0}, lac = {0,0,0,0};
    const f32x4 zero = {0,0,0,0};

    int krow  = 16 * wid + (lane >> 2);
    int kslot = lane & 3;
    const short* kg = kTb + (size_t)(jb + krow) * 32 + kslot * 8;
    int kw_ofs = krow * 32 + ((kslot ^ (krow & 3)) * 8);

    int vrow  = 8 * wid + (lane >> 3);
    int vslot = lane & 7;
    const short* vg = vBb + (size_t)vrow * N + jb + vslot * 8;
    int vw_ofs = vrow * 64 + ((vslot ^ (vrow & 7)) * 8);

    int kr_base = lr * 32 + ((lg ^ (lr & 3)) * 8);
    int vr0 = lr * 64, vr1 = (16 + lr) * 64;
    int sw0 = ((0 + lg) ^ (lr & 7)) * 8;
    int sw1 = ((4 + lg) ^ (lr & 7)) * 8;

    {   // prologue: stage tile 0 into buffer 0
        s16x8 kreg = *(const s16x8*)kg;
        s16x8 vreg = *(const s16x8*)vg;
        *(s16x8*)&pool[kw_ofs] = kreg;
        *(s16x8*)&pool[4096 + vw_ofs] = vreg;
    }
    __syncthreads();

    // 32 tiles: pairs (0,1)..(28,29), then 30 (stages 31), then 31 (no stage)
    for (int tt = 0; tt < 30; tt += 2) {
        STEP(0, tt + 1, true);
        STEP(1, tt + 2, true);
    }
    STEP(0, 31, true);
    STEP(1, 0, false);

    // epilogue: unnormalized partial O (bf16) + row-sum l (fp32)
    #pragma unroll
    for (int r = 0; r < 4; ++r) {
        pool[wid * 640 + (4 * lg + r) * 40 + lr]      = f2bf(o0[r]);
        pool[wid * 640 + (4 * lg + r) * 40 + 16 + lr] = f2bf(o1[r]);
    }
    if (lr == 0) {
        float* plp = pl + ((size_t)(s * 16 + bh)) * N + i0;
        #pragma unroll
        for (int r = 0; r < 4; ++r) plp[4 * lg + r] = lac[r];
    }
    short* pob = s ? po1 : po0;
    int il = lane >> 2, seg = lane & 3;
    s16x8 w = *(const s16x8*)&pool[wid * 640 + il * 40 + seg * 8];
    short* op = pob + ((size_t)bh * N + i0 + il) * 32 + seg * 8;
    *(s16x8*)op = w;
}

// ---------------- K6: out projection + residual; merge folded into staging --------
__global__ __launch_bounds__(256) void k_out(const short* __restrict__ wob,
        const short* __restrict__ po0, const short* __restrict__ po1,
        const float* __restrict__ pl, const float* __restrict__ bo,
        const float* __restrict__ x, float* __restrict__ out) {
    __shared__ __align__(16) short bs[8 * 32 * 32];   // 16KB: 8 h-tiles swizzled
    int mb = blockIdx.x, nb = blockIdx.y, b = blockIdx.z;
    int n0 = nb * 32;
    int t = threadIdx.x;
    int wid = t >> 6, lane = t & 63;
    int lr = lane & 15, lg = lane >> 4;
    int mw = mb * 64 + wid * 16;

    const short* ap_ = wob + (mw + lr) * C + lg * 8;
    s16x8 af[8];
    #pragma unroll
    for (int h = 0; h < 8; ++h) af[h] = *(const s16x8*)(ap_ + h * 32);

    {
        int h = t >> 5, idx = t & 31;
        size_t rb = ((size_t)(b * 8 + h)) * N + n0;
        const short* g0 = po0 + rb * 32;
        const short* g1 = po1 + rb * 32;
        const float* pl0 = pl + rb;
        const float* pl1 = pl + ((size_t)(16 + b * 8 + h)) * N + n0;
        #pragma unroll
        for (int i = 0; i < 4; ++i) {
            int chunk = idx + 32 * i;           // 0..127
            int r = chunk >> 2, sl = chunk & 3; // r: n-local 0..31
            s16x8 v0 = *(const s16x8*)(g0 + r * 32 + sl * 8);
            s16x8 v1 = *(const s16x8*)(g1 + r * 32 + sl * 8);
            float inv = 1.f / (pl0[r] + pl1[r]);
            s16x8 w;
            #pragma unroll
            for (int e = 0; e < 8; ++e)
                w[e] = f2bf((bf2f(v0[e]) + bf2f(v1[e])) * inv);
            *(s16x8*)&bs[h * 1024 + r * 32 + ((sl ^ (r & 3)) * 8)] = w;
        }
    }
    __syncthreads();

    f32x4 acc[2] = {{0,0,0,0},{0,0,0,0}};
    #pragma unroll
    for (int h = 0; h < 8; ++h) {
        #pragma unroll
        for (int f = 0; f < 2; ++f) {
            int row = f * 16 + lr;
            s16x8 xf = *(const s16x8*)&bs[h * 1024 + row * 32 + ((lg ^ (lr & 3)) * 8)];
            acc[f] = __builtin_amdgcn_mfma_f32_16x16x32_bf16(af[h], xf, acc[f], 0, 0, 0);
        }
    }

    float bvals[4];
    #pragma unroll
    for (int r = 0; r < 4; ++r) bvals[r] = bo[mw + 4 * lg + r];
    #pragma unroll
    for (int f = 0; f < 2; ++f) {
        int n = n0 + f * 16 + lr;
        #pragma unroll
        for (int r = 0; r < 4; ++r) {
            size_t idx = (size_t)(b * C + mw + 4 * lg + r) * N + n;
            out[idx] = acc[f][r] + bvals[r] + x[idx];
        }
    }
}

extern "C" void kernel_launch(void* const* d_in, const int* in_sizes, int n_in,
                              void* d_out, int out_size, void* d_ws, size_t ws_size,
                              hipStream_t stream) {
    const float* x  = (const float*)d_in[0];
    const float* gs = (const float*)d_in[1];
    const float* gb = (const float*)d_in[2];
    const float* wq = (const float*)d_in[3];
    const float* bq = (const float*)d_in[4];
    const float* wk = (const float*)d_in[5];
    const float* bk = (const float*)d_in[6];
    const float* wv = (const float*)d_in[7];
    const float* bv = (const float*)d_in[8];
    const float* wo = (const float*)d_in[9];
    const float* bo = (const float*)d_in[10];
    float* out = (float*)d_out;
    char* ws = (char*)d_ws;

    // Total ws usage: 0x14B0000 = 21.69 MB (< 22.02 MB proven safe).
    float2* partials = (float2*)(ws);           // 2 KB
    short*  wqkvb = (short*)(ws + 0x1000);      // 384 KB, dead after k_qkv
    float*  pl    = (float*)(ws + 0x1000);      // 512 KB, overlays dead wqkvb
    short*  wob   = (short*)(ws + 0x81000);     // 128 KB
    short*  xnT   = (short*)(ws + 0xB0000);     // 4 MB [b][n][c], dead after k_qkv
    short*  po1   = (short*)(ws + 0xB0000);     // 4 MB, overlays dead xnT
    short*  qT    = (short*)(ws + 0x4B0000);    // 4 MB [bh][n][32]
    short*  kT    = (short*)(ws + 0x8B0000);    // 4 MB [bh][n][32]
    short*  vB    = (short*)(ws + 0xCB0000);    // 4 MB [bh][32][n]
    short*  po0   = (short*)(ws + 0x10B0000);   // 4 MB [bh][n][32]

    k_stats<<<256, 256, 0, stream>>>(x, partials);
    k_wcvt <<<1024, 256, 0, stream>>>(wq, wk, wv, wo, wqkvb, wob);
    k_t    <<<512, 256, 0, stream>>>(x, gs, gb, partials, xnT);
    k_qkv  <<<dim3(12, 64, 2), 256, 0, stream>>>(wqkvb, xnT, bq, bk, bv, qT, kT, vB);
    k_attn <<<dim3(1024, 2), 256, 0, stream>>>(qT, kT, vB, po0, po1, pl);
    k_out  <<<dim3(4, 128, 2), 256, 0, stream>>>(wob, po0, po1, pl, bo, x, out);
}